// Round 1
// baseline (66.783 us; speedup 1.0000x reference)
//
#include <hip/hip_runtime.h>
#include <hip/hip_bf16.h>
#include <stdint.h>

// C[4096,10532] = inputs[4096,256] @ concat(lut,queue)[10532,256]^T  (fp32 out)
// Strategy: convert A/B to f16 in d_ws, then m97-style 128x128 MFMA GEMM.

#define M_DIM 4096
#define K_DIM 256
#define N_LUT 5532
#define N_Q   5000
#define N_DIM (N_LUT + N_Q)   // 10532
#define NT_M  32              // 4096/128
#define NT_N  83              // ceil(10532/128)
#define N_PAD (NT_N * 128)    // 10624

typedef _Float16 f16x8 __attribute__((ext_vector_type(8)));
typedef float f32x4 __attribute__((ext_vector_type(4)));

__device__ __forceinline__ unsigned short f2h(float f) {
  union { _Float16 h; unsigned short u; } v;
  v.h = (_Float16)f;   // v_cvt_f16_f32, RNE
  return v.u;
}

// ---------------- convert fp32 -> f16 into workspace ----------------
// Layout in ws: Abf[4096*256] halves, then Bbf[10624*256] halves (pad rows = 0)
__global__ __launch_bounds__(256) void convert_kernel(
    const float* __restrict__ inp, const float* __restrict__ lut,
    const float* __restrict__ que, unsigned short* __restrict__ Abf,
    unsigned short* __restrict__ Bbf) {
  const int AV = M_DIM * K_DIM / 4;  // 262144 float4s for A
  int i = blockIdx.x * 256 + threadIdx.x;  // grid sized exactly
  float4 x;
  unsigned short* dst;
  if (i < AV) {
    x = ((const float4*)inp)[i];
    dst = Abf + i * 4;
  } else {
    int e = (i - AV) * 4;          // element index in padded B
    int row = e >> 8;              // /256
    int col = e & 255;
    if (row < N_LUT)
      x = *(const float4*)(lut + (size_t)row * K_DIM + col);
    else if (row < N_DIM)
      x = *(const float4*)(que + (size_t)(row - N_LUT) * K_DIM + col);
    else
      x = make_float4(0.f, 0.f, 0.f, 0.f);
    dst = Bbf + e;
  }
  ushort4 o;
  o.x = f2h(x.x); o.y = f2h(x.y); o.z = f2h(x.z); o.w = f2h(x.w);
  *(ushort4*)dst = o;
}

// ---------------- GEMM: C = A * B^T, both [rows][K] f16 ----------------
#define GLDS16(gsrc, ldst)                                                  \
  __builtin_amdgcn_global_load_lds(                                         \
      (__attribute__((address_space(1))) void*)(gsrc),                      \
      (__attribute__((address_space(3))) void*)(ldst), 16, 0, 0)

__global__ __launch_bounds__(256, 2) void gemm_kernel(
    const unsigned short* __restrict__ A, const unsigned short* __restrict__ B,
    float* __restrict__ C) {
  __shared__ __align__(16) unsigned short As[128 * 64];  // 16 KB
  __shared__ __align__(16) unsigned short Bs[128 * 64];  // 16 KB

  const int t = threadIdx.x;
  const int lane = t & 63;
  const int wave = t >> 6;         // 4 waves
  const int wm = wave >> 1;        // 2x2 wave grid, each 64x64 output
  const int wn = wave & 1;

  // XCD-aware swizzle: nwg = 32*83 = 2656, divisible by 8
  const int nwg = NT_M * NT_N;
  const int cpx = nwg >> 3;        // 332
  int bid = blockIdx.x;
  int wg = (bid & 7) * cpx + (bid >> 3);
  const int bm = wg & 31;          // m-fast: consecutive wg share B panel
  const int bn = wg >> 5;
  const int brow = bm * 128;
  const int bcol = bn * 128;

  f32x4 acc[4][4] = {};

  const int lr = lane & 15;
  const int kg = (lane >> 4) * 8;  // k-offset of this lane's 8 contiguous elems

  for (int kt = 0; kt < 4; ++kt) {   // K = 256 = 4 * 64
    // stage 128x64 f16 tiles of A and B (16 KB each): 4 issues x 256 lanes x 16B
#pragma unroll
    for (int is = 0; is < 4; ++is) {
      int o = is * 4096 + t * 16;    // byte offset within tile
      int row = o >> 7;              // /128 bytes per row
      int cb = (o & 127) >> 1;       // col in elements
      const unsigned short* ga = A + (size_t)(brow + row) * K_DIM + kt * 64 + cb;
      const unsigned short* gb = B + (size_t)(bcol + row) * K_DIM + kt * 64 + cb;
      GLDS16(ga, As + is * 2048 + wave * 512);  // wave-uniform LDS base
      GLDS16(gb, Bs + is * 2048 + wave * 512);
    }
    __syncthreads();   // compiler emits vmcnt(0) drain before barrier

#pragma unroll
    for (int kk = 0; kk < 64; kk += 32) {
      f16x8 a[4], b[4];
#pragma unroll
      for (int i = 0; i < 4; ++i)
        a[i] = *(const f16x8*)&As[(wm * 64 + i * 16 + lr) * 64 + kk + kg];
#pragma unroll
      for (int j = 0; j < 4; ++j)
        b[j] = *(const f16x8*)&Bs[(wn * 64 + j * 16 + lr) * 64 + kk + kg];
#pragma unroll
      for (int i = 0; i < 4; ++i)
#pragma unroll
        for (int j = 0; j < 4; ++j)
          acc[i][j] = __builtin_amdgcn_mfma_f32_16x16x32_f16(a[i], b[j],
                                                             acc[i][j], 0, 0, 0);
    }
    __syncthreads();
  }

  // epilogue: C/D layout col = lane&15, row = (lane>>4)*4 + reg  [m89-verified]
  const int r0 = (lane >> 4) * 4;
#pragma unroll
  for (int j = 0; j < 4; ++j) {
    int col = bcol + wn * 64 + j * 16 + lr;
    if (col >= N_DIM) continue;   // N-boundary (last block covers 36 cols)
#pragma unroll
    for (int i = 0; i < 4; ++i) {
      size_t base = (size_t)(brow + wm * 64 + i * 16 + r0) * N_DIM + col;
#pragma unroll
      for (int r = 0; r < 4; ++r)
        C[base + (size_t)r * N_DIM] = acc[i][j][r];
    }
  }
}

extern "C" void kernel_launch(void* const* d_in, const int* in_sizes, int n_in,
                              void* d_out, int out_size, void* d_ws, size_t ws_size,
                              hipStream_t stream) {
  const float* inp = (const float*)d_in[0];   // inputs [4096,256]
  // d_in[1] targets, d_in[2] gt_flag: unused by the forward similarity
  const float* lut = (const float*)d_in[3];   // [5532,256]
  const float* que = (const float*)d_in[4];   // [5000,256]
  float* C = (float*)d_out;                   // [4096,10532]

  unsigned short* Abf = (unsigned short*)d_ws;
  unsigned short* Bbf = Abf + (size_t)M_DIM * K_DIM;  // needs ~7.6 MB of ws

  // exact grid: (4096*256 + 10624*256)/4 elems / 256 threads = 3680 blocks
  const int conv_blocks = (M_DIM * K_DIM / 4 + N_PAD * K_DIM / 4) / 256;
  convert_kernel<<<conv_blocks, 256, 0, stream>>>(inp, lut, que, Abf, Bbf);

  gemm_kernel<<<NT_M * NT_N, 256, 0, stream>>>(Abf, Bbf, C);
}